// Round 6
// baseline (464.208 us; speedup 1.0000x reference)
//
#include <hip/hip_runtime.h>
#include <math.h>

#define BB 8
#define CC 128
#define CH 64
#define HH 160
#define WW 160
#define HW (HH*WW)
#define PP 162            // padded width/height for conv2 input
#define INF __builtin_inff()

typedef __bf16 bfv8 __attribute__((ext_vector_type(8)));
typedef __bf16 bfv4 __attribute__((ext_vector_type(4)));
typedef float  f4   __attribute__((ext_vector_type(4)));

__device__ __forceinline__ float sgm(float z){ return 1.0f/(1.0f + __expf(-z)); }
__device__ __forceinline__ float silu_(float z){ return z/(1.0f + __expf(-z)); }
__device__ __forceinline__ f4 MFMA(bfv8 a, bfv8 b, f4 c){
  return __builtin_amdgcn_mfma_f32_16x16x32_bf16(a, b, c, 0, 0, 0);
}

// KPREP: bf16 weights (w2 transposed to [tap][oc][ic]) + folded BN scale/shift
__global__ __launch_bounds__(256) void kprep(const float* __restrict__ w1,
                                             const float* __restrict__ g1, const float* __restrict__ b1,
                                             const float* __restrict__ m1, const float* __restrict__ v1,
                                             const float* __restrict__ w2,
                                             const float* __restrict__ g2, const float* __restrict__ b2,
                                             const float* __restrict__ m2, const float* __restrict__ v2,
                                             const float* __restrict__ w3,
                                             const float* __restrict__ g3, const float* __restrict__ b3,
                                             const float* __restrict__ m3, const float* __restrict__ v3,
                                             __bf16* __restrict__ w1b, __bf16* __restrict__ w2b,
                                             __bf16* __restrict__ w3b, float* __restrict__ scsh){
  int t = blockIdx.x*256 + threadIdx.x;
  int stride = gridDim.x*256;
  for(int i=t; i<CH*CC; i+=stride) w1b[i] = (__bf16)w1[i];
  for(int i=t; i<CC*CH; i+=stride) w3b[i] = (__bf16)w3[i];
  for(int i=t; i<9*CH*CH; i+=stride){
    int tap = i >> 12; int rem = i & 4095; int oc = rem >> 6; int ic = rem & 63;
    w2b[i] = (__bf16)w2[(oc*CH + ic)*9 + tap];
  }
  if(t < CH){
    float s = g1[t]*rsqrtf(v1[t] + 1e-5f);
    scsh[t] = s; scsh[64+t] = b1[t] - m1[t]*s;
    float s2 = g2[t]*rsqrtf(v2[t] + 1e-5f);
    scsh[128+t] = s2; scsh[192+t] = b2[t] - m2[t]*s2;
  }
  if(t >= 64 && t < 64+CC){
    int c = t - 64;
    float s3 = g3[c]*rsqrtf(v3[c] + 1e-5f);
    scsh[256+c] = s3; scsh[384+c] = b3[c] - m3[c]*s3;
  }
}

// KZB: zero only the border of the padded conv2 input
__global__ __launch_bounds__(256) void kz_border(__bf16* __restrict__ o1p){
  int b = blockIdx.x;
  __bf16* base = o1p + (size_t)b*PP*PP*CH;
  int t = threadIdx.x;
  bfv4 z = {(__bf16)0.f,(__bf16)0.f,(__bf16)0.f,(__bf16)0.f};
  for(int i=t; i<644*16; i+=256){
    int e = i >> 4; int c4 = (i & 15)*4;
    int h, w;
    if(e < 162){ h = 0; w = e; }
    else if(e < 324){ h = 161; w = e - 162; }
    else if(e < 484){ h = e - 324 + 1; w = 0; }
    else { h = e - 484 + 1; w = 161; }
    *(bfv4*)(base + ((size_t)h*PP + w)*CH + c4) = z;
  }
}

// K12: fused stats + fill. One block per (b,c) plane; double-buffered 8-row
// batches keep ~24 loads in flight under the serial min/max chain.
// Load MECHANISM only changed vs last passing version — values, fmax/fmin
// order, and reduction trees identical (thr/chw bitwise stable).
__global__ __launch_bounds__(256) void k12(const float* __restrict__ x,
                                           const float* __restrict__ fsr,
                                           float* __restrict__ filled,
                                           float* __restrict__ chw){
  __shared__ float ra[256], rb[256];
  __shared__ float sb[2];
  int bc = blockIdx.x;
  int c  = bc & (CC-1);
  int t  = threadIdx.x;
  const float* xp = x + (size_t)bc*HW;
  bool act  = t < WW;
  bool hasL = t > 0, hasR = t < WW-1;

  // ---- pass 1 ----
  float mn = INF, sum = 0.f;
  float Mp=-INF, mp=INF, Mc=-INF, mc=INF;
  if(act){
    float C0=xp[t];
    float L0=hasL?xp[t-1]:0.f, R0=hasR?xp[t+1]:0.f;
    float ML=hasL?L0:-INF, MR=hasR?R0:-INF, mL=hasL?L0:INF, mR=hasR?R0:INF;
    Mc=fmaxf(C0,fmaxf(ML,MR)); mc=fminf(C0,fminf(mL,mR)); mn=C0;
  }
  float Lb[2][8], Cb[2][8], Rb[2][8];
  #pragma unroll
  for(int k=0;k<8;++k){
    int hr=1+k;
    if(act && hr<HH){
      const float* rp = xp + hr*WW;
      Lb[0][k]=hasL?rp[t-1]:0.f; Cb[0][k]=rp[t]; Rb[0][k]=hasR?rp[t+1]:0.f;
    } else { Lb[0][k]=0.f; Cb[0][k]=0.f; Rb[0][k]=0.f; }
  }
  int cur=0;
  for(int h0=0; h0<HH; h0+=8){
    if(h0+8 < HH){
      #pragma unroll
      for(int k=0;k<8;++k){
        int hr=h0+9+k;
        if(act && hr<HH){
          const float* rp = xp + hr*WW;
          Lb[cur^1][k]=hasL?rp[t-1]:0.f; Cb[cur^1][k]=rp[t]; Rb[cur^1][k]=hasR?rp[t+1]:0.f;
        } else { Lb[cur^1][k]=0.f; Cb[cur^1][k]=0.f; Rb[cur^1][k]=0.f; }
      }
    }
    if(act){
      #pragma unroll
      for(int k=0;k<8;++k){
        int hr=h0+1+k;
        float Mn, mr;
        if(hr<HH){
          float Lk=Lb[cur][k], Ck=Cb[cur][k], Rk=Rb[cur][k];
          float ML=hasL?Lk:-INF, MR=hasR?Rk:-INF, mL=hasL?Lk:INF, mRr=hasR?Rk:INF;
          Mn=fmaxf(Ck,fmaxf(ML,MR)); mr=fminf(Ck,fminf(mL,mRr));
          mn=fminf(mn,Ck);
        } else { Mn=-INF; mr=INF; }
        sum += fmaxf(fmaxf(Mp,Mc),Mn) - fminf(fminf(mp,mc),mr);
        Mp=Mc; mp=mc; Mc=Mn; mc=mr;
      }
    }
    cur ^= 1;
  }
  ra[t]=mn; rb[t]=sum; __syncthreads();
  for(int s=128; s>0; s>>=1){
    if(t < s){ ra[t]=fminf(ra[t],ra[t+s]); rb[t]+=rb[t+s]; }
    __syncthreads();
  }
  if(t==0){ sb[0]=ra[0]; sb[1]=0.3f*(rb[0]/(float)HW + 1e-6f); }
  __syncthreads();
  float base = sb[0], th = sb[1];
  float s = sgm(fsr[c]);

  // ---- pass 2 ----
  float* fp = filled + (size_t)bc*HW;
  float amax=0.f, asum=0.f;
  Mp=-INF; mp=INF; Mc=-INF; mc=INF;
  float cen = 0.f;
  if(act){
    float C0=xp[t];
    float L0=hasL?xp[t-1]:0.f, R0=hasR?xp[t+1]:0.f;
    float ML=hasL?L0:-INF, MR=hasR?R0:-INF, mL=hasL?L0:INF, mR=hasR?R0:INF;
    Mc=fmaxf(C0,fmaxf(ML,MR)); mc=fminf(C0,fminf(mL,mR)); cen=C0;
  }
  #pragma unroll
  for(int k=0;k<8;++k){
    int hr=1+k;
    if(act && hr<HH){
      const float* rp = xp + hr*WW;
      Lb[0][k]=hasL?rp[t-1]:0.f; Cb[0][k]=rp[t]; Rb[0][k]=hasR?rp[t+1]:0.f;
    } else { Lb[0][k]=0.f; Cb[0][k]=0.f; Rb[0][k]=0.f; }
  }
  cur=0;
  for(int h0=0; h0<HH; h0+=8){
    if(h0+8 < HH){
      #pragma unroll
      for(int k=0;k<8;++k){
        int hr=h0+9+k;
        if(act && hr<HH){
          const float* rp = xp + hr*WW;
          Lb[cur^1][k]=hasL?rp[t-1]:0.f; Cb[cur^1][k]=rp[t]; Rb[cur^1][k]=hasR?rp[t+1]:0.f;
        } else { Lb[cur^1][k]=0.f; Cb[cur^1][k]=0.f; Rb[cur^1][k]=0.f; }
      }
    }
    if(act){
      #pragma unroll
      for(int k=0;k<8;++k){
        int hr=h0+1+k;
        int h = h0+k;
        float Mn, mr;
        if(hr<HH){
          float Lk=Lb[cur][k], Ck=Cb[cur][k], Rk=Rb[cur][k];
          float ML=hasL?Lk:-INF, MR=hasR?Rk:-INF, mL=hasL?Lk:INF, mRr=hasR?Rk:INF;
          Mn=fmaxf(Ck,fmaxf(ML,MR)); mr=fminf(Ck,fminf(mL,mRr));
        } else { Mn=-INF; mr=INF; }
        float contrast = fmaxf(fmaxf(Mp,Mc),Mn) - fminf(fminf(mp,mc),mr);
        float f = (contrast < th) ? cen*(1.f-s) + base*s : cen;
        fp[h*WW + t] = f;
        float a = fabsf(f);
        amax = fmaxf(amax, a); asum += a;
        Mp=Mc; mp=mc; Mc=Mn; mc=mr; cen = Cb[cur][k];
      }
    }
    cur ^= 1;
  }
  ra[t]=amax; rb[t]=asum; __syncthreads();
  for(int st=128; st>0; st>>=1){
    if(t < st){ ra[t]=fmaxf(ra[t],ra[t+st]); rb[t]+=rb[t+st]; }
    __syncthreads();
  }
  if(t==0) chw[bc] = sgm(3.0f*(ra[0] - rb[0]/(float)HW - 0.3f));
}

// K3: xs[b,p] = mean_c |filled|
__global__ __launch_bounds__(256) void k3_xs(const float* __restrict__ filled,
                                             float* __restrict__ xs){
  int i = blockIdx.x*256 + threadIdx.x;
  int b = i / (HW/4); int p4 = (i - b*(HW/4))*4;
  const float* fp = filled + (size_t)b*CC*HW + p4;
  f4 s = {0.f,0.f,0.f,0.f};
  #pragma unroll 4
  for(int c=0; c<CC; ++c){
    f4 v = *(const f4*)(fp + (size_t)c*HW);
    s.x += fabsf(v.x); s.y += fabsf(v.y); s.z += fabsf(v.z); s.w += fabsf(v.w);
  }
  f4 r = {s.x*(1.f/CC), s.y*(1.f/CC), s.z*(1.f/CC), s.w*(1.f/CC)};
  *(f4*)(xs + (size_t)b*HW + p4) = r;
}

// K_ENH: enh[b][p][ic] (NHWC bf16) = filled * chw * (1+ew), ew computed
// inline from xs (3x3 clipped window; smooth sigmoid -> reassoc-safe).
__global__ __launch_bounds__(256) void k_enh(const float* __restrict__ filled,
                                             const float* __restrict__ chw,
                                             const float* __restrict__ xs,
                                             __bf16* __restrict__ enh){
  __shared__ __bf16 tile[64][132];
  __shared__ float ewl[64];
  int b  = blockIdx.x / 400;
  int p0 = (blockIdx.x % 400) * 64;
  int t  = threadIdx.x;
  if(t < 64){
    int p = p0 + t; int h = p/WW, w = p - h*WW;
    const float* xpb = xs + (size_t)b*HW;
    int h0 = h>0?h-1:0, h1 = h<HH-1?h+1:h;
    int w0 = w>0?w-1:0, w1 = w<WW-1?w+1:w;
    float M = -INF, m = INF;
    for(int hh=h0; hh<=h1; ++hh)
      for(int ww=w0; ww<=w1; ++ww){
        float v = xpb[hh*WW+ww]; M = fmaxf(M,v); m = fminf(m,v);
      }
    ewl[t] = sgm(5.0f*((M-m) - 0.5f));
  }
  __syncthreads();
  #pragma unroll 4
  for(int e=0; e<32; ++e){
    int idx = e*256 + t; int ic = idx >> 6; int p = idx & 63;
    float v = filled[((size_t)(b*CC + ic))*HW + p0 + p];
    float g = chw[b*CC + ic] * (1.f + ewl[p]);
    tile[p][ic] = (__bf16)(v * g);
  }
  __syncthreads();
  #pragma unroll
  for(int e=0; e<8; ++e){
    int idx = e*256 + t; int p = idx >> 5; int icg = idx & 31;
    bfv4 v = *(const bfv4*)&tile[p][icg*4];
    *(bfv4*)&enh[((size_t)(b*HW + p0 + p))*CC + icg*4] = v;
  }
}

// C1: o1p(padded NHWC bf16) = silu(bn1(w1 @ enh))
__global__ __launch_bounds__(256) void c1_mfma(const __bf16* __restrict__ enh,
                                               const __bf16* __restrict__ w1b,
                                               const float* __restrict__ scsh,
                                               __bf16* __restrict__ o1p){
  int lane = threadIdx.x & 63, wv = threadIdx.x >> 6;
  int u = blockIdx.x*4 + wv;            // 2560 units: b(8) x h(160) x half(2)
  int b = u / 320; int r = u % 320; int h = r >> 1; int w0base = (r & 1)*80;
  int q = lane >> 4, j = lane & 15;
  bfv8 afr[4][4];
  #pragma unroll
  for(int mt=0; mt<4; ++mt)
    #pragma unroll
    for(int kk=0; kk<4; ++kk)
      afr[mt][kk] = *(const bfv8*)&w1b[(mt*16 + j)*CC + kk*32 + q*8];
  f4 sc4[4], sh4[4];
  #pragma unroll
  for(int mt=0; mt<4; ++mt){
    sc4[mt] = *(const f4*)&scsh[mt*16 + q*4];
    sh4[mt] = *(const f4*)&scsh[64 + mt*16 + q*4];
  }
  const __bf16* ebase = enh + (size_t)b*HW*CC;
  __bf16* obase = o1p + (size_t)b*PP*PP*CH;
  for(int s5=0; s5<5; ++s5){
    int w0 = w0base + s5*16;
    int p0 = h*WW + w0;
    const __bf16* bp = ebase + (size_t)(p0 + j)*CC + q*8;
    bfv8 bf[4];
    #pragma unroll
    for(int kk=0; kk<4; ++kk) bf[kk] = *(const bfv8*)(bp + kk*32);
    f4 acc[4] = {{0,0,0,0},{0,0,0,0},{0,0,0,0},{0,0,0,0}};
    #pragma unroll
    for(int kk=0; kk<4; ++kk)
      #pragma unroll
      for(int mt=0; mt<4; ++mt)
        acc[mt] = MFMA(afr[mt][kk], bf[kk], acc[mt]);
    int w = w0 + j;
    __bf16* op = obase + ((size_t)(h+1)*PP + (w+1))*CH + q*4;
    #pragma unroll
    for(int mt=0; mt<4; ++mt){
      bfv4 ov;
      #pragma unroll
      for(int rr=0; rr<4; ++rr){
        float z = acc[mt][rr]*sc4[mt][rr] + sh4[mt][rr];
        ov[rr] = (__bf16)silu_(z);
      }
      *(bfv4*)(op + mt*16) = ov;
    }
  }
}

// C2: o2(NHWC bf16) = silu(bn2(conv3x3(o1p, w2b))). 2 output rows/wave,
// 4 independent MFMA chains, all 24 tile loads batched before compute.
__global__ __launch_bounds__(256) void c2_mfma(const __bf16* __restrict__ o1p,
                                               const __bf16* __restrict__ w2b,
                                               const float* __restrict__ scsh,
                                               __bf16* __restrict__ o2){
  int lane = threadIdx.x & 63, mt = threadIdx.x >> 6;
  int u = blockIdx.x;                       // 1280: b(8) x hp(80) x wh(2)
  int b = u / 160; int r = u % 160; int hp = r >> 1; int wh = r & 1;
  int h0 = hp*2;
  int w0base = wh*80;
  int q = lane >> 4, j = lane & 15;
  bfv8 afr[9][2];
  #pragma unroll
  for(int t=0; t<9; ++t)
    #pragma unroll
    for(int icb=0; icb<2; ++icb)
      afr[t][icb] = *(const bfv8*)&w2b[(t*CH + mt*16 + j)*CH + icb*32 + q*8];
  f4 sc4 = *(const f4*)&scsh[128 + mt*16 + q*4];
  f4 sh4 = *(const f4*)&scsh[192 + mt*16 + q*4];
  const __bf16* ibase = o1p + (size_t)b*PP*PP*CH;
  __bf16* obase = o2 + (size_t)b*HW*CH;
  for(int s5=0; s5<5; ++s5){
    int w0 = w0base + s5*16;
    bfv8 bv[4][3][2];
    #pragma unroll
    for(int r4=0; r4<4; ++r4){
      const __bf16* rp = ibase + ((size_t)(h0+r4)*PP + w0 + j)*CH + q*8;
      #pragma unroll
      for(int dw=0; dw<3; ++dw)
        #pragma unroll
        for(int icb=0; icb<2; ++icb)
          bv[r4][dw][icb] = *(const bfv8*)(rp + dw*CH + icb*32);
    }
    f4 a00={0,0,0,0}, a01={0,0,0,0}, a10={0,0,0,0}, a11={0,0,0,0};
    #pragma unroll
    for(int dh=0; dh<3; ++dh)
      #pragma unroll
      for(int dw=0; dw<3; ++dw){
        int t = dh*3+dw;
        a00 = MFMA(afr[t][0], bv[dh  ][dw][0], a00);
        a01 = MFMA(afr[t][1], bv[dh  ][dw][1], a01);
        a10 = MFMA(afr[t][0], bv[dh+1][dw][0], a10);
        a11 = MFMA(afr[t][1], bv[dh+1][dw][1], a11);
      }
    f4 acc0 = a00 + a01, acc1 = a10 + a11;
    __bf16* op0 = obase + ((size_t)(h0*WW + w0 + j))*CH + mt*16 + q*4;
    __bf16* op1 = obase + ((size_t)((h0+1)*WW + w0 + j))*CH + mt*16 + q*4;
    bfv4 ov0, ov1;
    #pragma unroll
    for(int rr=0; rr<4; ++rr){
      ov0[rr] = (__bf16)silu_(acc0[rr]*sc4[rr] + sh4[rr]);
      ov1[rr] = (__bf16)silu_(acc1[rr]*sc4[rr] + sh4[rr]);
    }
    *(bfv4*)op0 = ov0;
    *(bfv4*)op1 = ov1;
  }
}

// C3: out(NCHW f32) = silu(bn3(w3 @ o2) + enh). Block = 64px x 128oc,
// residual read straight from enh (bf16 NHWC), LDS-transposed coalesced store.
__global__ __launch_bounds__(256) void c3_mfma(const __bf16* __restrict__ o2,
                                               const __bf16* __restrict__ w3b,
                                               const float* __restrict__ scsh,
                                               const __bf16* __restrict__ enh,
                                               float* __restrict__ out){
  __shared__ float ot[CC][66];
  int lane = threadIdx.x & 63, wv = threadIdx.x >> 6;
  int b = blockIdx.x / 400; int p0 = (blockIdx.x % 400)*64;
  int q = lane >> 4, j = lane & 15;
  int px0 = wv*16;
  int pix = p0 + px0 + j;
  const __bf16* bp = o2 + ((size_t)b*HW + pix)*CH + q*8;
  bfv8 bf0 = *(const bfv8*)bp;
  bfv8 bf1 = *(const bfv8*)(bp + 32);
  f4 acc[8];
  #pragma unroll
  for(int mt=0; mt<8; ++mt){
    bfv8 a0 = *(const bfv8*)&w3b[(mt*16 + j)*CH + q*8];
    bfv8 a1 = *(const bfv8*)&w3b[(mt*16 + j)*CH + 32 + q*8];
    f4 z = {0.f,0.f,0.f,0.f};
    z = MFMA(a0, bf0, z);
    z = MFMA(a1, bf1, z);
    acc[mt] = z;
  }
  const __bf16* ep = enh + ((size_t)b*HW + pix)*CC;
  #pragma unroll
  for(int mt=0; mt<8; ++mt){
    f4 scg = *(const f4*)&scsh[256 + mt*16 + q*4];
    f4 shg = *(const f4*)&scsh[384 + mt*16 + q*4];
    bfv4 e4 = *(const bfv4*)(ep + mt*16 + q*4);
    #pragma unroll
    for(int rr=0; rr<4; ++rr){
      float z = acc[mt][rr]*scg[rr] + shg[rr] + (float)e4[rr];
      ot[mt*16 + q*4 + rr][px0 + j] = silu_(z);
    }
  }
  __syncthreads();
  int t = threadIdx.x;
  #pragma unroll
  for(int e=0; e<8; ++e){
    int oc = e*16 + (t >> 4);
    int c4 = (t & 15)*4;
    f4 v = *(const f4*)&ot[oc][c4];
    *(f4*)&out[((size_t)(b*CC + oc))*HW + p0 + c4] = v;
  }
}

extern "C" void kernel_launch(void* const* d_in, const int* in_sizes, int n_in,
                              void* d_out, int out_size, void* d_ws, size_t ws_size,
                              hipStream_t stream) {
  const float* x   = (const float*)d_in[0];
  const float* fsr = (const float*)d_in[1];
  const float* w1  = (const float*)d_in[2];
  const float* g1  = (const float*)d_in[3];
  const float* b1  = (const float*)d_in[4];
  const float* m1  = (const float*)d_in[5];
  const float* v1  = (const float*)d_in[6];
  const float* w2  = (const float*)d_in[7];
  const float* g2  = (const float*)d_in[8];
  const float* b2  = (const float*)d_in[9];
  const float* m2  = (const float*)d_in[10];
  const float* v2  = (const float*)d_in[11];
  const float* w3  = (const float*)d_in[12];
  const float* g3  = (const float*)d_in[13];
  const float* b3  = (const float*)d_in[14];
  const float* m3  = (const float*)d_in[15];
  const float* v3  = (const float*)d_in[16];
  float* out = (float*)d_out;

  char* wp = (char*)d_ws;
  float*  filled = (float*)wp;   wp += (size_t)BB*CC*HW*4;       // 104.9 MB
  __bf16* enh    = (__bf16*)wp;  wp += (size_t)BB*HW*CC*2;       // 52.4 MB
  __bf16* o1p    = (__bf16*)wp;  wp += (size_t)BB*PP*PP*CH*2;    // 26.9 MB
  __bf16* o2b    = (__bf16*)wp;  wp += (size_t)BB*HW*CH*2;       // 26.2 MB
  float*  xs     = (float*)wp;   wp += (size_t)BB*HW*4;
  float*  chw    = (float*)wp;   wp += 1024*4;
  __bf16* w1b    = (__bf16*)wp;  wp += (size_t)CH*CC*2;
  __bf16* w3b    = (__bf16*)wp;  wp += (size_t)CC*CH*2;
  __bf16* w2b    = (__bf16*)wp;  wp += (size_t)9*CH*CH*2;
  float*  scsh   = (float*)wp;   wp += 512*4;

  kprep    <<<dim3(64), dim3(256), 0, stream>>>(w1,g1,b1,m1,v1, w2,g2,b2,m2,v2,
                                                w3,g3,b3,m3,v3, w1b,w2b,w3b,scsh);
  kz_border<<<dim3(BB), dim3(256), 0, stream>>>(o1p);
  k12      <<<dim3(BB*CC), dim3(256), 0, stream>>>(x, fsr, filled, chw);
  k3_xs    <<<dim3(BB*HW/4/256), dim3(256), 0, stream>>>(filled, xs);
  k_enh    <<<dim3(BB*400), dim3(256), 0, stream>>>(filled, chw, xs, enh);
  c1_mfma  <<<dim3(640), dim3(256), 0, stream>>>(enh, w1b, scsh, o1p);
  c2_mfma  <<<dim3(1280), dim3(256), 0, stream>>>(o1p, w2b, scsh, o2b);
  c3_mfma  <<<dim3(3200), dim3(256), 0, stream>>>(o2b, w3b, scsh, enh, out);
}

// Round 7
// 283.360 us; speedup vs baseline: 1.6382x; 1.6382x over previous
//
#include <hip/hip_runtime.h>
#include <math.h>

#define BB 8
#define CC 128
#define CH 64
#define HH 160
#define WW 160
#define HW (HH*WW)
#define PP 162            // padded width/height for conv2 input
#define INF __builtin_inff()

typedef __bf16 bfv8 __attribute__((ext_vector_type(8)));
typedef __bf16 bfv4 __attribute__((ext_vector_type(4)));
typedef float  f4   __attribute__((ext_vector_type(4)));

__device__ __forceinline__ float sgm(float z){ return 1.0f/(1.0f + __expf(-z)); }
__device__ __forceinline__ float silu_(float z){ return z/(1.0f + __expf(-z)); }
__device__ __forceinline__ f4 MFMA(bfv8 a, bfv8 b, f4 c){
  return __builtin_amdgcn_mfma_f32_16x16x32_bf16(a, b, c, 0, 0, 0);
}

// KPREP: bf16 weights (w2 transposed to [tap][oc][ic]) + folded BN scale/shift
__global__ __launch_bounds__(256) void kprep(const float* __restrict__ w1,
                                             const float* __restrict__ g1, const float* __restrict__ b1,
                                             const float* __restrict__ m1, const float* __restrict__ v1,
                                             const float* __restrict__ w2,
                                             const float* __restrict__ g2, const float* __restrict__ b2,
                                             const float* __restrict__ m2, const float* __restrict__ v2,
                                             const float* __restrict__ w3,
                                             const float* __restrict__ g3, const float* __restrict__ b3,
                                             const float* __restrict__ m3, const float* __restrict__ v3,
                                             __bf16* __restrict__ w1b, __bf16* __restrict__ w2b,
                                             __bf16* __restrict__ w3b, float* __restrict__ scsh){
  int t = blockIdx.x*256 + threadIdx.x;
  int stride = gridDim.x*256;
  for(int i=t; i<CH*CC; i+=stride) w1b[i] = (__bf16)w1[i];
  for(int i=t; i<CC*CH; i+=stride) w3b[i] = (__bf16)w3[i];
  for(int i=t; i<9*CH*CH; i+=stride){
    int tap = i >> 12; int rem = i & 4095; int oc = rem >> 6; int ic = rem & 63;
    w2b[i] = (__bf16)w2[(oc*CH + ic)*9 + tap];
  }
  if(t < CH){
    float s = g1[t]*rsqrtf(v1[t] + 1e-5f);
    scsh[t] = s; scsh[64+t] = b1[t] - m1[t]*s;
    float s2 = g2[t]*rsqrtf(v2[t] + 1e-5f);
    scsh[128+t] = s2; scsh[192+t] = b2[t] - m2[t]*s2;
  }
  if(t >= 64 && t < 64+CC){
    int c = t - 64;
    float s3 = g3[c]*rsqrtf(v3[c] + 1e-5f);
    scsh[256+c] = s3; scsh[384+c] = b3[c] - m3[c]*s3;
  }
}

// KZB: zero only the border of the padded conv2 input
__global__ __launch_bounds__(256) void kz_border(__bf16* __restrict__ o1p){
  int b = blockIdx.x;
  __bf16* base = o1p + (size_t)b*PP*PP*CH;
  int t = threadIdx.x;
  bfv4 z = {(__bf16)0.f,(__bf16)0.f,(__bf16)0.f,(__bf16)0.f};
  for(int i=t; i<644*16; i+=256){
    int e = i >> 4; int c4 = (i & 15)*4;
    int h, w;
    if(e < 162){ h = 0; w = e; }
    else if(e < 324){ h = 161; w = e - 162; }
    else if(e < 484){ h = e - 324 + 1; w = 0; }
    else { h = e - 484 + 1; w = 161; }
    *(bfv4*)(base + ((size_t)h*PP + w)*CH + c4) = z;
  }
}

// ---- k12 helpers: STATIC buffer names only (rule: no runtime array idx) ----
__device__ __forceinline__ void load8(const float* __restrict__ xp, int t,
                                      bool act, bool hasL, bool hasR, int start,
                                      float (&Lb)[8], float (&Cb)[8], float (&Rb)[8]){
  #pragma unroll
  for(int k=0;k<8;++k){
    int hr = start + k;
    if(act && hr < HH){
      const float* rp = xp + hr*WW;
      Lb[k] = hasL ? rp[t-1] : 0.f; Cb[k] = rp[t]; Rb[k] = hasR ? rp[t+1] : 0.f;
    } else { Lb[k]=0.f; Cb[k]=0.f; Rb[k]=0.f; }
  }
}

__device__ __forceinline__ void proc1(int base, bool hasL, bool hasR,
                                      const float (&Lb)[8], const float (&Cb)[8], const float (&Rb)[8],
                                      float& Mp, float& mp, float& Mc, float& mc,
                                      float& mn, float& sum){
  #pragma unroll
  for(int k=0;k<8;++k){
    int hr = base + 1 + k;
    float Mn, mr;
    if(hr < HH){
      float Lk=Lb[k], Ck=Cb[k], Rk=Rb[k];
      float ML=hasL?Lk:-INF, MR=hasR?Rk:-INF, mL=hasL?Lk:INF, mRr=hasR?Rk:INF;
      Mn = fmaxf(Ck, fmaxf(ML,MR)); mr = fminf(Ck, fminf(mL,mRr));
      mn = fminf(mn, Ck);
    } else { Mn = -INF; mr = INF; }
    sum += fmaxf(fmaxf(Mp,Mc),Mn) - fminf(fminf(mp,mc),mr);
    Mp=Mc; mp=mc; Mc=Mn; mc=mr;
  }
}

__device__ __forceinline__ void proc2(int base, int t, bool hasL, bool hasR,
                                      const float (&Lb)[8], const float (&Cb)[8], const float (&Rb)[8],
                                      float& Mp, float& mp, float& Mc, float& mc,
                                      float& cen, float& amax, float& asum,
                                      float th, float basev, float s,
                                      float* __restrict__ fp){
  #pragma unroll
  for(int k=0;k<8;++k){
    int hr = base + 1 + k;
    int h  = base + k;
    float Mn, mr;
    if(hr < HH){
      float Lk=Lb[k], Ck=Cb[k], Rk=Rb[k];
      float ML=hasL?Lk:-INF, MR=hasR?Rk:-INF, mL=hasL?Lk:INF, mRr=hasR?Rk:INF;
      Mn = fmaxf(Ck, fmaxf(ML,MR)); mr = fminf(Ck, fminf(mL,mRr));
    } else { Mn = -INF; mr = INF; }
    float contrast = fmaxf(fmaxf(Mp,Mc),Mn) - fminf(fminf(mp,mc),mr);
    float f = (contrast < th) ? cen*(1.f-s) + basev*s : cen;
    fp[h*WW + t] = f;
    float a = fabsf(f);
    amax = fmaxf(amax, a); asum += a;
    Mp=Mc; mp=mc; Mc=Mn; mc=mr; cen = Cb[k];
  }
}

// K12: fused stats + fill. One block per (b,c) plane; software-pipelined
// 8-row batches in two STATICALLY-NAMED buffers (A,B) so everything stays
// in registers. Values / fmax order / reductions identical to passing R5.
__global__ __launch_bounds__(256) void k12(const float* __restrict__ x,
                                           const float* __restrict__ fsr,
                                           float* __restrict__ filled,
                                           float* __restrict__ chw){
  __shared__ float ra[256], rb[256];
  __shared__ float sb[2];
  int bc = blockIdx.x;
  int c  = bc & (CC-1);
  int t  = threadIdx.x;
  const float* xp = x + (size_t)bc*HW;
  bool act  = t < WW;
  bool hasL = t > 0, hasR = t < WW-1;

  float LA[8], CA[8], RA[8], LB2[8], CB2[8], RB2[8];

  // ---- pass 1 ----
  float mn = INF, sum = 0.f;
  float Mp=-INF, mp=INF, Mc=-INF, mc=INF;
  if(act){
    float C0=xp[t];
    float L0=hasL?xp[t-1]:0.f, R0=hasR?xp[t+1]:0.f;
    float ML=hasL?L0:-INF, MR=hasR?R0:-INF, mL=hasL?L0:INF, mR=hasR?R0:INF;
    Mc=fmaxf(C0,fmaxf(ML,MR)); mc=fminf(C0,fminf(mL,mR)); mn=C0;
  }
  load8(xp, t, act, hasL, hasR, 1, LA, CA, RA);
  for(int h0=0; h0<HH; h0+=16){
    load8(xp, t, act, hasL, hasR, h0+9, LB2, CB2, RB2);
    if(act) proc1(h0,   hasL, hasR, LA, CA, RA, Mp, mp, Mc, mc, mn, sum);
    if(h0+16 < HH) load8(xp, t, act, hasL, hasR, h0+17, LA, CA, RA);
    if(act) proc1(h0+8, hasL, hasR, LB2, CB2, RB2, Mp, mp, Mc, mc, mn, sum);
  }
  ra[t]=mn; rb[t]=sum; __syncthreads();
  for(int s=128; s>0; s>>=1){
    if(t < s){ ra[t]=fminf(ra[t],ra[t+s]); rb[t]+=rb[t+s]; }
    __syncthreads();
  }
  if(t==0){ sb[0]=ra[0]; sb[1]=0.3f*(rb[0]/(float)HW + 1e-6f); }
  __syncthreads();
  float base = sb[0], th = sb[1];
  float s = sgm(fsr[c]);

  // ---- pass 2 ----
  float* fp = filled + (size_t)bc*HW;
  float amax=0.f, asum=0.f;
  Mp=-INF; mp=INF; Mc=-INF; mc=INF;
  float cen = 0.f;
  if(act){
    float C0=xp[t];
    float L0=hasL?xp[t-1]:0.f, R0=hasR?xp[t+1]:0.f;
    float ML=hasL?L0:-INF, MR=hasR?R0:-INF, mL=hasL?L0:INF, mR=hasR?R0:INF;
    Mc=fmaxf(C0,fmaxf(ML,MR)); mc=fminf(C0,fminf(mL,mR)); cen=C0;
  }
  load8(xp, t, act, hasL, hasR, 1, LA, CA, RA);
  for(int h0=0; h0<HH; h0+=16){
    load8(xp, t, act, hasL, hasR, h0+9, LB2, CB2, RB2);
    if(act) proc2(h0,   t, hasL, hasR, LA, CA, RA, Mp, mp, Mc, mc, cen, amax, asum, th, base, s, fp);
    if(h0+16 < HH) load8(xp, t, act, hasL, hasR, h0+17, LA, CA, RA);
    if(act) proc2(h0+8, t, hasL, hasR, LB2, CB2, RB2, Mp, mp, Mc, mc, cen, amax, asum, th, base, s, fp);
  }
  ra[t]=amax; rb[t]=asum; __syncthreads();
  for(int st=128; st>0; st>>=1){
    if(t < st){ ra[t]=fmaxf(ra[t],ra[t+st]); rb[t]+=rb[t+st]; }
    __syncthreads();
  }
  if(t==0) chw[bc] = sgm(3.0f*(ra[0] - rb[0]/(float)HW - 0.3f));
}

// K3: xs[b,p] = mean_c |filled|
__global__ __launch_bounds__(256) void k3_xs(const float* __restrict__ filled,
                                             float* __restrict__ xs){
  int i = blockIdx.x*256 + threadIdx.x;
  int b = i / (HW/4); int p4 = (i - b*(HW/4))*4;
  const float* fp = filled + (size_t)b*CC*HW + p4;
  f4 s = {0.f,0.f,0.f,0.f};
  #pragma unroll 4
  for(int c=0; c<CC; ++c){
    f4 v = *(const f4*)(fp + (size_t)c*HW);
    s.x += fabsf(v.x); s.y += fabsf(v.y); s.z += fabsf(v.z); s.w += fabsf(v.w);
  }
  f4 r = {s.x*(1.f/CC), s.y*(1.f/CC), s.z*(1.f/CC), s.w*(1.f/CC)};
  *(f4*)(xs + (size_t)b*HW + p4) = r;
}

// K_ENH: enh[b][p][ic] (NHWC bf16) = filled * chw * (1+ew), ew computed
// inline from xs (3x3 clipped window; smooth sigmoid -> reassoc-safe).
__global__ __launch_bounds__(256) void k_enh(const float* __restrict__ filled,
                                             const float* __restrict__ chw,
                                             const float* __restrict__ xs,
                                             __bf16* __restrict__ enh){
  __shared__ __bf16 tile[64][132];
  __shared__ float ewl[64];
  int b  = blockIdx.x / 400;
  int p0 = (blockIdx.x % 400) * 64;
  int t  = threadIdx.x;
  if(t < 64){
    int p = p0 + t; int h = p/WW, w = p - h*WW;
    const float* xpb = xs + (size_t)b*HW;
    int h0 = h>0?h-1:0, h1 = h<HH-1?h+1:h;
    int w0 = w>0?w-1:0, w1 = w<WW-1?w+1:w;
    float M = -INF, m = INF;
    for(int hh=h0; hh<=h1; ++hh)
      for(int ww=w0; ww<=w1; ++ww){
        float v = xpb[hh*WW+ww]; M = fmaxf(M,v); m = fminf(m,v);
      }
    ewl[t] = sgm(5.0f*((M-m) - 0.5f));
  }
  __syncthreads();
  #pragma unroll 4
  for(int e=0; e<32; ++e){
    int idx = e*256 + t; int ic = idx >> 6; int p = idx & 63;
    float v = filled[((size_t)(b*CC + ic))*HW + p0 + p];
    float g = chw[b*CC + ic] * (1.f + ewl[p]);
    tile[p][ic] = (__bf16)(v * g);
  }
  __syncthreads();
  #pragma unroll
  for(int e=0; e<8; ++e){
    int idx = e*256 + t; int p = idx >> 5; int icg = idx & 31;
    bfv4 v = *(const bfv4*)&tile[p][icg*4];
    *(bfv4*)&enh[((size_t)(b*HW + p0 + p))*CC + icg*4] = v;
  }
}

// C1: o1p(padded NHWC bf16) = silu(bn1(w1 @ enh))
__global__ __launch_bounds__(256) void c1_mfma(const __bf16* __restrict__ enh,
                                               const __bf16* __restrict__ w1b,
                                               const float* __restrict__ scsh,
                                               __bf16* __restrict__ o1p){
  int lane = threadIdx.x & 63, wv = threadIdx.x >> 6;
  int u = blockIdx.x*4 + wv;            // 2560 units: b(8) x h(160) x half(2)
  int b = u / 320; int r = u % 320; int h = r >> 1; int w0base = (r & 1)*80;
  int q = lane >> 4, j = lane & 15;
  bfv8 afr[4][4];
  #pragma unroll
  for(int mt=0; mt<4; ++mt)
    #pragma unroll
    for(int kk=0; kk<4; ++kk)
      afr[mt][kk] = *(const bfv8*)&w1b[(mt*16 + j)*CC + kk*32 + q*8];
  f4 sc4[4], sh4[4];
  #pragma unroll
  for(int mt=0; mt<4; ++mt){
    sc4[mt] = *(const f4*)&scsh[mt*16 + q*4];
    sh4[mt] = *(const f4*)&scsh[64 + mt*16 + q*4];
  }
  const __bf16* ebase = enh + (size_t)b*HW*CC;
  __bf16* obase = o1p + (size_t)b*PP*PP*CH;
  for(int s5=0; s5<5; ++s5){
    int w0 = w0base + s5*16;
    int p0 = h*WW + w0;
    const __bf16* bp = ebase + (size_t)(p0 + j)*CC + q*8;
    bfv8 bf[4];
    #pragma unroll
    for(int kk=0; kk<4; ++kk) bf[kk] = *(const bfv8*)(bp + kk*32);
    f4 acc[4] = {{0,0,0,0},{0,0,0,0},{0,0,0,0},{0,0,0,0}};
    #pragma unroll
    for(int kk=0; kk<4; ++kk)
      #pragma unroll
      for(int mt=0; mt<4; ++mt)
        acc[mt] = MFMA(afr[mt][kk], bf[kk], acc[mt]);
    int w = w0 + j;
    __bf16* op = obase + ((size_t)(h+1)*PP + (w+1))*CH + q*4;
    #pragma unroll
    for(int mt=0; mt<4; ++mt){
      bfv4 ov;
      #pragma unroll
      for(int rr=0; rr<4; ++rr){
        float z = acc[mt][rr]*sc4[mt][rr] + sh4[mt][rr];
        ov[rr] = (__bf16)silu_(z);
      }
      *(bfv4*)(op + mt*16) = ov;
    }
  }
}

// C2: o2(NHWC bf16) = silu(bn2(conv3x3(o1p, w2b))). 2 output rows/wave,
// 4 independent MFMA chains, all 24 tile loads batched before compute.
__global__ __launch_bounds__(256) void c2_mfma(const __bf16* __restrict__ o1p,
                                               const __bf16* __restrict__ w2b,
                                               const float* __restrict__ scsh,
                                               __bf16* __restrict__ o2){
  int lane = threadIdx.x & 63, mt = threadIdx.x >> 6;
  int u = blockIdx.x;                       // 1280: b(8) x hp(80) x wh(2)
  int b = u / 160; int r = u % 160; int hp = r >> 1; int wh = r & 1;
  int h0 = hp*2;
  int w0base = wh*80;
  int q = lane >> 4, j = lane & 15;
  bfv8 afr[9][2];
  #pragma unroll
  for(int t=0; t<9; ++t)
    #pragma unroll
    for(int icb=0; icb<2; ++icb)
      afr[t][icb] = *(const bfv8*)&w2b[(t*CH + mt*16 + j)*CH + icb*32 + q*8];
  f4 sc4 = *(const f4*)&scsh[128 + mt*16 + q*4];
  f4 sh4 = *(const f4*)&scsh[192 + mt*16 + q*4];
  const __bf16* ibase = o1p + (size_t)b*PP*PP*CH;
  __bf16* obase = o2 + (size_t)b*HW*CH;
  for(int s5=0; s5<5; ++s5){
    int w0 = w0base + s5*16;
    bfv8 bv[4][3][2];
    #pragma unroll
    for(int r4=0; r4<4; ++r4){
      const __bf16* rp = ibase + ((size_t)(h0+r4)*PP + w0 + j)*CH + q*8;
      #pragma unroll
      for(int dw=0; dw<3; ++dw)
        #pragma unroll
        for(int icb=0; icb<2; ++icb)
          bv[r4][dw][icb] = *(const bfv8*)(rp + dw*CH + icb*32);
    }
    f4 a00={0,0,0,0}, a01={0,0,0,0}, a10={0,0,0,0}, a11={0,0,0,0};
    #pragma unroll
    for(int dh=0; dh<3; ++dh)
      #pragma unroll
      for(int dw=0; dw<3; ++dw){
        int t = dh*3+dw;
        a00 = MFMA(afr[t][0], bv[dh  ][dw][0], a00);
        a01 = MFMA(afr[t][1], bv[dh  ][dw][1], a01);
        a10 = MFMA(afr[t][0], bv[dh+1][dw][0], a10);
        a11 = MFMA(afr[t][1], bv[dh+1][dw][1], a11);
      }
    f4 acc0 = a00 + a01, acc1 = a10 + a11;
    __bf16* op0 = obase + ((size_t)(h0*WW + w0 + j))*CH + mt*16 + q*4;
    __bf16* op1 = obase + ((size_t)((h0+1)*WW + w0 + j))*CH + mt*16 + q*4;
    bfv4 ov0, ov1;
    #pragma unroll
    for(int rr=0; rr<4; ++rr){
      ov0[rr] = (__bf16)silu_(acc0[rr]*sc4[rr] + sh4[rr]);
      ov1[rr] = (__bf16)silu_(acc1[rr]*sc4[rr] + sh4[rr]);
    }
    *(bfv4*)op0 = ov0;
    *(bfv4*)op1 = ov1;
  }
}

// C3: out(NCHW f32) = silu(bn3(w3 @ o2) + enh). Block = 64px x 128oc,
// residual read straight from enh (bf16 NHWC), LDS-transposed coalesced store.
__global__ __launch_bounds__(256) void c3_mfma(const __bf16* __restrict__ o2,
                                               const __bf16* __restrict__ w3b,
                                               const float* __restrict__ scsh,
                                               const __bf16* __restrict__ enh,
                                               float* __restrict__ out){
  __shared__ float ot[CC][66];
  int lane = threadIdx.x & 63, wv = threadIdx.x >> 6;
  int b = blockIdx.x / 400; int p0 = (blockIdx.x % 400)*64;
  int q = lane >> 4, j = lane & 15;
  int px0 = wv*16;
  int pix = p0 + px0 + j;
  const __bf16* bp = o2 + ((size_t)b*HW + pix)*CH + q*8;
  bfv8 bf0 = *(const bfv8*)bp;
  bfv8 bf1 = *(const bfv8*)(bp + 32);
  f4 acc[8];
  #pragma unroll
  for(int mt=0; mt<8; ++mt){
    bfv8 a0 = *(const bfv8*)&w3b[(mt*16 + j)*CH + q*8];
    bfv8 a1 = *(const bfv8*)&w3b[(mt*16 + j)*CH + 32 + q*8];
    f4 z = {0.f,0.f,0.f,0.f};
    z = MFMA(a0, bf0, z);
    z = MFMA(a1, bf1, z);
    acc[mt] = z;
  }
  const __bf16* ep = enh + ((size_t)b*HW + pix)*CC;
  #pragma unroll
  for(int mt=0; mt<8; ++mt){
    f4 scg = *(const f4*)&scsh[256 + mt*16 + q*4];
    f4 shg = *(const f4*)&scsh[384 + mt*16 + q*4];
    bfv4 e4 = *(const bfv4*)(ep + mt*16 + q*4);
    #pragma unroll
    for(int rr=0; rr<4; ++rr){
      float z = acc[mt][rr]*scg[rr] + shg[rr] + (float)e4[rr];
      ot[mt*16 + q*4 + rr][px0 + j] = silu_(z);
    }
  }
  __syncthreads();
  int t = threadIdx.x;
  #pragma unroll
  for(int e=0; e<8; ++e){
    int oc = e*16 + (t >> 4);
    int c4 = (t & 15)*4;
    f4 v = *(const f4*)&ot[oc][c4];
    *(f4*)&out[((size_t)(b*CC + oc))*HW + p0 + c4] = v;
  }
}

extern "C" void kernel_launch(void* const* d_in, const int* in_sizes, int n_in,
                              void* d_out, int out_size, void* d_ws, size_t ws_size,
                              hipStream_t stream) {
  const float* x   = (const float*)d_in[0];
  const float* fsr = (const float*)d_in[1];
  const float* w1  = (const float*)d_in[2];
  const float* g1  = (const float*)d_in[3];
  const float* b1  = (const float*)d_in[4];
  const float* m1  = (const float*)d_in[5];
  const float* v1  = (const float*)d_in[6];
  const float* w2  = (const float*)d_in[7];
  const float* g2  = (const float*)d_in[8];
  const float* b2  = (const float*)d_in[9];
  const float* m2  = (const float*)d_in[10];
  const float* v2  = (const float*)d_in[11];
  const float* w3  = (const float*)d_in[12];
  const float* g3  = (const float*)d_in[13];
  const float* b3  = (const float*)d_in[14];
  const float* m3  = (const float*)d_in[15];
  const float* v3  = (const float*)d_in[16];
  float* out = (float*)d_out;

  char* wp = (char*)d_ws;
  float*  filled = (float*)wp;   wp += (size_t)BB*CC*HW*4;       // 104.9 MB
  __bf16* enh    = (__bf16*)wp;  wp += (size_t)BB*HW*CC*2;       // 52.4 MB
  __bf16* o1p    = (__bf16*)wp;  wp += (size_t)BB*PP*PP*CH*2;    // 26.9 MB
  __bf16* o2b    = (__bf16*)wp;  wp += (size_t)BB*HW*CH*2;       // 26.2 MB
  float*  xs     = (float*)wp;   wp += (size_t)BB*HW*4;
  float*  chw    = (float*)wp;   wp += 1024*4;
  __bf16* w1b    = (__bf16*)wp;  wp += (size_t)CH*CC*2;
  __bf16* w3b    = (__bf16*)wp;  wp += (size_t)CC*CH*2;
  __bf16* w2b    = (__bf16*)wp;  wp += (size_t)9*CH*CH*2;
  float*  scsh   = (float*)wp;   wp += 512*4;

  kprep    <<<dim3(64), dim3(256), 0, stream>>>(w1,g1,b1,m1,v1, w2,g2,b2,m2,v2,
                                                w3,g3,b3,m3,v3, w1b,w2b,w3b,scsh);
  kz_border<<<dim3(BB), dim3(256), 0, stream>>>(o1p);
  k12      <<<dim3(BB*CC), dim3(256), 0, stream>>>(x, fsr, filled, chw);
  k3_xs    <<<dim3(BB*HW/4/256), dim3(256), 0, stream>>>(filled, xs);
  k_enh    <<<dim3(BB*400), dim3(256), 0, stream>>>(filled, chw, xs, enh);
  c1_mfma  <<<dim3(640), dim3(256), 0, stream>>>(enh, w1b, scsh, o1p);
  c2_mfma  <<<dim3(1280), dim3(256), 0, stream>>>(o1p, w2b, scsh, o2b);
  c3_mfma  <<<dim3(3200), dim3(256), 0, stream>>>(o2b, w3b, scsh, out ? enh : enh, out);
}

// Round 8
// 209.399 us; speedup vs baseline: 2.2169x; 1.3532x over previous
//
#include <hip/hip_runtime.h>
#include <math.h>

#define BB 8
#define CC 128
#define CH 64
#define HH 160
#define WW 160
#define HW (HH*WW)
#define PP 162            // padded width/height for conv2 input
#define INF __builtin_inff()

typedef __bf16 bfv8 __attribute__((ext_vector_type(8)));
typedef __bf16 bfv4 __attribute__((ext_vector_type(4)));
typedef __bf16 bfv2 __attribute__((ext_vector_type(2)));
typedef float  f4   __attribute__((ext_vector_type(4)));

__device__ __forceinline__ float sgm(float z){ return 1.0f/(1.0f + __expf(-z)); }
__device__ __forceinline__ float silu_(float z){ return z/(1.0f + __expf(-z)); }
__device__ __forceinline__ f4 MFMA(bfv8 a, bfv8 b, f4 c){
  return __builtin_amdgcn_mfma_f32_16x16x32_bf16(a, b, c, 0, 0, 0);
}

// KPREP: bf16 weights (w2 transposed to [tap][oc][ic]) + folded BN scale/shift
__global__ __launch_bounds__(256) void kprep(const float* __restrict__ w1,
                                             const float* __restrict__ g1, const float* __restrict__ b1,
                                             const float* __restrict__ m1, const float* __restrict__ v1,
                                             const float* __restrict__ w2,
                                             const float* __restrict__ g2, const float* __restrict__ b2,
                                             const float* __restrict__ m2, const float* __restrict__ v2,
                                             const float* __restrict__ w3,
                                             const float* __restrict__ g3, const float* __restrict__ b3,
                                             const float* __restrict__ m3, const float* __restrict__ v3,
                                             __bf16* __restrict__ w1b, __bf16* __restrict__ w2b,
                                             __bf16* __restrict__ w3b, float* __restrict__ scsh){
  int t = blockIdx.x*256 + threadIdx.x;
  int stride = gridDim.x*256;
  for(int i=t; i<CH*CC; i+=stride) w1b[i] = (__bf16)w1[i];
  for(int i=t; i<CC*CH; i+=stride) w3b[i] = (__bf16)w3[i];
  for(int i=t; i<9*CH*CH; i+=stride){
    int tap = i >> 12; int rem = i & 4095; int oc = rem >> 6; int ic = rem & 63;
    w2b[i] = (__bf16)w2[(oc*CH + ic)*9 + tap];
  }
  if(t < CH){
    float s = g1[t]*rsqrtf(v1[t] + 1e-5f);
    scsh[t] = s; scsh[64+t] = b1[t] - m1[t]*s;
    float s2 = g2[t]*rsqrtf(v2[t] + 1e-5f);
    scsh[128+t] = s2; scsh[192+t] = b2[t] - m2[t]*s2;
  }
  if(t >= 64 && t < 64+CC){
    int c = t - 64;
    float s3 = g3[c]*rsqrtf(v3[c] + 1e-5f);
    scsh[256+c] = s3; scsh[384+c] = b3[c] - m3[c]*s3;
  }
}

// KZB: zero only the border of the padded conv2 input
__global__ __launch_bounds__(256) void kz_border(__bf16* __restrict__ o1p){
  int b = blockIdx.x;
  __bf16* base = o1p + (size_t)b*PP*PP*CH;
  int t = threadIdx.x;
  bfv4 z = {(__bf16)0.f,(__bf16)0.f,(__bf16)0.f,(__bf16)0.f};
  for(int i=t; i<644*16; i+=256){
    int e = i >> 4; int c4 = (i & 15)*4;
    int h, w;
    if(e < 162){ h = 0; w = e; }
    else if(e < 324){ h = 161; w = e - 162; }
    else if(e < 484){ h = e - 324 + 1; w = 0; }
    else { h = e - 484 + 1; w = 161; }
    *(bfv4*)(base + ((size_t)h*PP + w)*CH + c4) = z;
  }
}

// ---- k12 helpers: STATIC buffer names only ----
__device__ __forceinline__ void load8(const float* __restrict__ xp, int t,
                                      bool act, bool hasL, bool hasR, int start,
                                      float (&Lb)[8], float (&Cb)[8], float (&Rb)[8]){
  #pragma unroll
  for(int k=0;k<8;++k){
    int hr = start + k;
    if(act && hr < HH){
      const float* rp = xp + hr*WW;
      Lb[k] = hasL ? rp[t-1] : 0.f; Cb[k] = rp[t]; Rb[k] = hasR ? rp[t+1] : 0.f;
    } else { Lb[k]=0.f; Cb[k]=0.f; Rb[k]=0.f; }
  }
}

__device__ __forceinline__ void proc1(int base, bool hasL, bool hasR,
                                      const float (&Lb)[8], const float (&Cb)[8], const float (&Rb)[8],
                                      float& Mp, float& mp, float& Mc, float& mc,
                                      float& mn, float& sum){
  #pragma unroll
  for(int k=0;k<8;++k){
    int hr = base + 1 + k;
    float Mn, mr;
    if(hr < HH){
      float Lk=Lb[k], Ck=Cb[k], Rk=Rb[k];
      float ML=hasL?Lk:-INF, MR=hasR?Rk:-INF, mL=hasL?Lk:INF, mRr=hasR?Rk:INF;
      Mn = fmaxf(Ck, fmaxf(ML,MR)); mr = fminf(Ck, fminf(mL,mRr));
      mn = fminf(mn, Ck);
    } else { Mn = -INF; mr = INF; }
    sum += fmaxf(fmaxf(Mp,Mc),Mn) - fminf(fminf(mp,mc),mr);
    Mp=Mc; mp=mc; Mc=Mn; mc=mr;
  }
}

__device__ __forceinline__ void proc2(int base, int t, bool hasL, bool hasR,
                                      const float (&Lb)[8], const float (&Cb)[8], const float (&Rb)[8],
                                      float& Mp, float& mp, float& Mc, float& mc,
                                      float& cen, float& amax, float& asum,
                                      float th, float basev, float s,
                                      __bf16* __restrict__ fp){
  #pragma unroll
  for(int k=0;k<8;++k){
    int hr = base + 1 + k;
    int h  = base + k;
    float Mn, mr;
    if(hr < HH){
      float Lk=Lb[k], Ck=Cb[k], Rk=Rb[k];
      float ML=hasL?Lk:-INF, MR=hasR?Rk:-INF, mL=hasL?Lk:INF, mRr=hasR?Rk:INF;
      Mn = fmaxf(Ck, fmaxf(ML,MR)); mr = fminf(Ck, fminf(mL,mRr));
    } else { Mn = -INF; mr = INF; }
    float contrast = fmaxf(fmaxf(Mp,Mc),Mn) - fminf(fminf(mp,mc),mr);
    float f = (contrast < th) ? cen*(1.f-s) + basev*s : cen;
    fp[h*WW + t] = (__bf16)f;                 // bf16 store; stats stay f32
    float a = fabsf(f);
    amax = fmaxf(amax, a); asum += a;
    Mp=Mc; mp=mc; Mc=Mn; mc=mr; cen = Cb[k];
  }
}

// K12: fused stats + fill (bf16 out). Pipelined static A/B row batches.
__global__ __launch_bounds__(256) void k12(const float* __restrict__ x,
                                           const float* __restrict__ fsr,
                                           __bf16* __restrict__ fill16,
                                           float* __restrict__ chw){
  __shared__ float ra[256], rb[256];
  __shared__ float sb[2];
  int bc = blockIdx.x;
  int c  = bc & (CC-1);
  int t  = threadIdx.x;
  const float* xp = x + (size_t)bc*HW;
  bool act  = t < WW;
  bool hasL = t > 0, hasR = t < WW-1;

  float LA[8], CA[8], RA[8], LB2[8], CB2[8], RB2[8];

  // ---- pass 1 ----
  float mn = INF, sum = 0.f;
  float Mp=-INF, mp=INF, Mc=-INF, mc=INF;
  if(act){
    float C0=xp[t];
    float L0=hasL?xp[t-1]:0.f, R0=hasR?xp[t+1]:0.f;
    float ML=hasL?L0:-INF, MR=hasR?R0:-INF, mL=hasL?L0:INF, mR=hasR?R0:INF;
    Mc=fmaxf(C0,fmaxf(ML,MR)); mc=fminf(C0,fminf(mL,mR)); mn=C0;
  }
  load8(xp, t, act, hasL, hasR, 1, LA, CA, RA);
  for(int h0=0; h0<HH; h0+=16){
    load8(xp, t, act, hasL, hasR, h0+9, LB2, CB2, RB2);
    if(act) proc1(h0,   hasL, hasR, LA, CA, RA, Mp, mp, Mc, mc, mn, sum);
    if(h0+16 < HH) load8(xp, t, act, hasL, hasR, h0+17, LA, CA, RA);
    if(act) proc1(h0+8, hasL, hasR, LB2, CB2, RB2, Mp, mp, Mc, mc, mn, sum);
  }
  ra[t]=mn; rb[t]=sum; __syncthreads();
  for(int s=128; s>0; s>>=1){
    if(t < s){ ra[t]=fminf(ra[t],ra[t+s]); rb[t]+=rb[t+s]; }
    __syncthreads();
  }
  if(t==0){ sb[0]=ra[0]; sb[1]=0.3f*(rb[0]/(float)HW + 1e-6f); }
  __syncthreads();
  float base = sb[0], th = sb[1];
  float s = sgm(fsr[c]);

  // ---- pass 2 ----
  __bf16* fp = fill16 + (size_t)bc*HW;
  float amax=0.f, asum=0.f;
  Mp=-INF; mp=INF; Mc=-INF; mc=INF;
  float cen = 0.f;
  if(act){
    float C0=xp[t];
    float L0=hasL?xp[t-1]:0.f, R0=hasR?xp[t+1]:0.f;
    float ML=hasL?L0:-INF, MR=hasR?R0:-INF, mL=hasL?L0:INF, mR=hasR?R0:INF;
    Mc=fmaxf(C0,fmaxf(ML,MR)); mc=fminf(C0,fminf(mL,mR)); cen=C0;
  }
  load8(xp, t, act, hasL, hasR, 1, LA, CA, RA);
  for(int h0=0; h0<HH; h0+=16){
    load8(xp, t, act, hasL, hasR, h0+9, LB2, CB2, RB2);
    if(act) proc2(h0,   t, hasL, hasR, LA, CA, RA, Mp, mp, Mc, mc, cen, amax, asum, th, base, s, fp);
    if(h0+16 < HH) load8(xp, t, act, hasL, hasR, h0+17, LA, CA, RA);
    if(act) proc2(h0+8, t, hasL, hasR, LB2, CB2, RB2, Mp, mp, Mc, mc, cen, amax, asum, th, base, s, fp);
  }
  ra[t]=amax; rb[t]=asum; __syncthreads();
  for(int st=128; st>0; st>>=1){
    if(t < st){ ra[t]=fmaxf(ra[t],ra[t+st]); rb[t]+=rb[t+st]; }
    __syncthreads();
  }
  if(t==0) chw[bc] = sgm(3.0f*(ra[0] - rb[0]/(float)HW - 0.3f));
}

// K3: xs[b,p] = mean_c |fill16|, bfv8 loads (8 px/thread)
__global__ __launch_bounds__(256) void k3_xs(const __bf16* __restrict__ fill16,
                                             float* __restrict__ xs){
  int i = blockIdx.x*256 + threadIdx.x;       // BB*HW/8 = 25600 units
  int b = i / (HW/8); int p8 = (i - b*(HW/8))*8;
  const __bf16* fp = fill16 + (size_t)b*CC*HW + p8;
  float s0=0,s1=0,s2=0,s3=0,s4=0,s5=0,s6=0,s7=0;
  #pragma unroll 4
  for(int c=0; c<CC; ++c){
    bfv8 v = *(const bfv8*)(fp + (size_t)c*HW);
    s0 += fabsf((float)v[0]); s1 += fabsf((float)v[1]);
    s2 += fabsf((float)v[2]); s3 += fabsf((float)v[3]);
    s4 += fabsf((float)v[4]); s5 += fabsf((float)v[5]);
    s6 += fabsf((float)v[6]); s7 += fabsf((float)v[7]);
  }
  f4 r0 = {s0*(1.f/CC), s1*(1.f/CC), s2*(1.f/CC), s3*(1.f/CC)};
  f4 r1 = {s4*(1.f/CC), s5*(1.f/CC), s6*(1.f/CC), s7*(1.f/CC)};
  *(f4*)(xs + (size_t)b*HW + p8)     = r0;
  *(f4*)(xs + (size_t)b*HW + p8 + 4) = r1;
}

// K_ENH: enh[b][p][ic] (NHWC bf16) = fill16 * chw * (1+ew), ew inline from xs
__global__ __launch_bounds__(256) void k_enh(const __bf16* __restrict__ fill16,
                                             const float* __restrict__ chw,
                                             const float* __restrict__ xs,
                                             __bf16* __restrict__ enh){
  __shared__ __bf16 tile[64][132];
  __shared__ float ewl[64];
  int b  = blockIdx.x / 400;
  int p0 = (blockIdx.x % 400) * 64;
  int t  = threadIdx.x;
  if(t < 64){
    int p = p0 + t; int h = p/WW, w = p - h*WW;
    const float* xpb = xs + (size_t)b*HW;
    int h0 = h>0?h-1:0, h1 = h<HH-1?h+1:h;
    int w0 = w>0?w-1:0, w1 = w<WW-1?w+1:w;
    float M = -INF, m = INF;
    for(int hh=h0; hh<=h1; ++hh)
      for(int ww=w0; ww<=w1; ++ww){
        float v = xpb[hh*WW+ww]; M = fmaxf(M,v); m = fminf(m,v);
      }
    ewl[t] = sgm(5.0f*((M-m) - 0.5f));
  }
  __syncthreads();
  #pragma unroll 4
  for(int e=0; e<16; ++e){
    int idx = e*256 + t; int ic = idx >> 5; int pp = (idx & 31)*2;
    bfv2 v = *(const bfv2*)(fill16 + ((size_t)(b*CC + ic))*HW + p0 + pp);
    float g = chw[b*CC + ic];
    tile[pp  ][ic] = (__bf16)((float)v[0] * g * (1.f + ewl[pp]));
    tile[pp+1][ic] = (__bf16)((float)v[1] * g * (1.f + ewl[pp+1]));
  }
  __syncthreads();
  #pragma unroll
  for(int e=0; e<8; ++e){
    int idx = e*256 + t; int p = idx >> 5; int icg = idx & 31;
    bfv4 v = *(const bfv4*)&tile[p][icg*4];
    *(bfv4*)&enh[((size_t)(b*HW + p0 + p))*CC + icg*4] = v;
  }
}

// C1: o1p(padded NHWC bf16) = silu(bn1(w1 @ enh))
__global__ __launch_bounds__(256) void c1_mfma(const __bf16* __restrict__ enh,
                                               const __bf16* __restrict__ w1b,
                                               const float* __restrict__ scsh,
                                               __bf16* __restrict__ o1p){
  int lane = threadIdx.x & 63, wv = threadIdx.x >> 6;
  int u = blockIdx.x*4 + wv;            // 2560 units: b(8) x h(160) x half(2)
  int b = u / 320; int r = u % 320; int h = r >> 1; int w0base = (r & 1)*80;
  int q = lane >> 4, j = lane & 15;
  bfv8 afr[4][4];
  #pragma unroll
  for(int mt=0; mt<4; ++mt)
    #pragma unroll
    for(int kk=0; kk<4; ++kk)
      afr[mt][kk] = *(const bfv8*)&w1b[(mt*16 + j)*CC + kk*32 + q*8];
  f4 sc4[4], sh4[4];
  #pragma unroll
  for(int mt=0; mt<4; ++mt){
    sc4[mt] = *(const f4*)&scsh[mt*16 + q*4];
    sh4[mt] = *(const f4*)&scsh[64 + mt*16 + q*4];
  }
  const __bf16* ebase = enh + (size_t)b*HW*CC;
  __bf16* obase = o1p + (size_t)b*PP*PP*CH;
  for(int s5=0; s5<5; ++s5){
    int w0 = w0base + s5*16;
    int p0 = h*WW + w0;
    const __bf16* bp = ebase + (size_t)(p0 + j)*CC + q*8;
    bfv8 bf[4];
    #pragma unroll
    for(int kk=0; kk<4; ++kk) bf[kk] = *(const bfv8*)(bp + kk*32);
    f4 acc[4] = {{0,0,0,0},{0,0,0,0},{0,0,0,0},{0,0,0,0}};
    #pragma unroll
    for(int kk=0; kk<4; ++kk)
      #pragma unroll
      for(int mt=0; mt<4; ++mt)
        acc[mt] = MFMA(afr[mt][kk], bf[kk], acc[mt]);
    int w = w0 + j;
    __bf16* op = obase + ((size_t)(h+1)*PP + (w+1))*CH + q*4;
    #pragma unroll
    for(int mt=0; mt<4; ++mt){
      bfv4 ov;
      #pragma unroll
      for(int rr=0; rr<4; ++rr){
        float z = acc[mt][rr]*sc4[mt][rr] + sh4[mt][rr];
        ov[rr] = (__bf16)silu_(z);
      }
      *(bfv4*)(op + mt*16) = ov;
    }
  }
}

// C2: o2 = silu(bn2(conv3x3(o1p))). Input tile (4 rows x 82 cols x 64ch)
// staged ONCE per block into XOR-swizzled LDS via global_load_lds with
// per-lane pre-swizzled SOURCE (linear dest). All 4 waves share it.
// MFMA accumulation order identical to previous passing version.
__global__ __launch_bounds__(256) void c2_mfma(const __bf16* __restrict__ o1p,
                                               const __bf16* __restrict__ w2b,
                                               const float* __restrict__ scsh,
                                               __bf16* __restrict__ o2){
  __shared__ __bf16 lds[4*82*64];          // 41984 B, swizzled chunks of 8 bf16
  int lane = threadIdx.x & 63, mt = threadIdx.x >> 6;
  int u = blockIdx.x;                       // 1280: b(8) x hp(80) x wh(2)
  int b = u / 160; int r_ = u % 160; int hp = r_ >> 1; int wh = r_ & 1;
  int h0 = hp*2;
  int wstart = wh*80;
  int q = lane >> 4, j = lane & 15;
  const __bf16* ibase = o1p + (size_t)b*PP*PP*CH;

  // stage: chunk i -> (r = i/656, w = (i%656)>>3, slot kp = i&7);
  // fetch logical k = kp ^ (w&7) so that read-side XOR finds it.
  {
    int t = threadIdx.x;
    int wvbase = t & ~63;
    #pragma unroll
    for(int it=0; it<11; ++it){
      int i = it*256 + t;
      if(i < 2624){
        int r = i / 656; int rem = i - r*656;
        int w = rem >> 3; int kp = rem & 7;
        int k = kp ^ (w & 7);
        const __bf16* src = ibase + ((size_t)(h0+r)*PP + wstart + w)*CH + k*8;
        char* dst = (char*)lds + (size_t)(it*256 + wvbase)*16;
        __builtin_amdgcn_global_load_lds((const __attribute__((address_space(1))) void*)src,
                                         (__attribute__((address_space(3))) void*)dst,
                                         16, 0, 0);
      }
    }
  }
  // weights (independent of staging)
  bfv8 afr[9][2];
  #pragma unroll
  for(int t=0; t<9; ++t)
    #pragma unroll
    for(int icb=0; icb<2; ++icb)
      afr[t][icb] = *(const bfv8*)&w2b[(t*CH + mt*16 + j)*CH + icb*32 + q*8];
  f4 sc4 = *(const f4*)&scsh[128 + mt*16 + q*4];
  f4 sh4 = *(const f4*)&scsh[192 + mt*16 + q*4];
  asm volatile("s_waitcnt vmcnt(0)" ::: "memory");
  __syncthreads();

  __bf16* obase = o2 + (size_t)b*HW*CH;
  for(int s5=0; s5<5; ++s5){
    int wb = s5*16;
    f4 a00={0,0,0,0}, a01={0,0,0,0}, a10={0,0,0,0}, a11={0,0,0,0};
    #pragma unroll
    for(int r=0; r<4; ++r){
      bfv8 bv0[3], bv1[3];
      #pragma unroll
      for(int dw=0; dw<3; ++dw){
        int wl = wb + j + dw;
        int basee = r*5248 + wl*64;              // elems: (r*656 + wl*8)*8
        int k0 = q ^ (wl & 7);
        bv0[dw] = *(const bfv8*)&lds[basee + k0*8];
        bv1[dw] = *(const bfv8*)&lds[basee + (k0^4)*8];
      }
      #pragma unroll
      for(int dw=0; dw<3; ++dw){
        if(r < 3){
          a00 = MFMA(afr[r*3+dw][0], bv0[dw], a00);
          a01 = MFMA(afr[r*3+dw][1], bv1[dw], a01);
        }
        if(r >= 1){
          a10 = MFMA(afr[(r-1)*3+dw][0], bv0[dw], a10);
          a11 = MFMA(afr[(r-1)*3+dw][1], bv1[dw], a11);
        }
      }
    }
    f4 acc0 = a00 + a01, acc1 = a10 + a11;
    int w0 = wstart + wb;
    __bf16* op0 = obase + ((size_t)(h0*WW + w0 + j))*CH + mt*16 + q*4;
    __bf16* op1 = obase + ((size_t)((h0+1)*WW + w0 + j))*CH + mt*16 + q*4;
    bfv4 ov0, ov1;
    #pragma unroll
    for(int rr=0; rr<4; ++rr){
      ov0[rr] = (__bf16)silu_(acc0[rr]*sc4[rr] + sh4[rr]);
      ov1[rr] = (__bf16)silu_(acc1[rr]*sc4[rr] + sh4[rr]);
    }
    *(bfv4*)op0 = ov0;
    *(bfv4*)op1 = ov1;
  }
}

// C3: out(NCHW f32) = silu(bn3(w3 @ o2) + enh), LDS-transposed coalesced store
__global__ __launch_bounds__(256) void c3_mfma(const __bf16* __restrict__ o2,
                                               const __bf16* __restrict__ w3b,
                                               const float* __restrict__ scsh,
                                               const __bf16* __restrict__ enh,
                                               float* __restrict__ out){
  __shared__ float ot[CC][66];
  int lane = threadIdx.x & 63, wv = threadIdx.x >> 6;
  int b = blockIdx.x / 400; int p0 = (blockIdx.x % 400)*64;
  int q = lane >> 4, j = lane & 15;
  int px0 = wv*16;
  int pix = p0 + px0 + j;
  const __bf16* bp = o2 + ((size_t)b*HW + pix)*CH + q*8;
  bfv8 bf0 = *(const bfv8*)bp;
  bfv8 bf1 = *(const bfv8*)(bp + 32);
  f4 acc[8];
  #pragma unroll
  for(int mt=0; mt<8; ++mt){
    bfv8 a0 = *(const bfv8*)&w3b[(mt*16 + j)*CH + q*8];
    bfv8 a1 = *(const bfv8*)&w3b[(mt*16 + j)*CH + 32 + q*8];
    f4 z = {0.f,0.f,0.f,0.f};
    z = MFMA(a0, bf0, z);
    z = MFMA(a1, bf1, z);
    acc[mt] = z;
  }
  const __bf16* ep = enh + ((size_t)b*HW + pix)*CC;
  #pragma unroll
  for(int mt=0; mt<8; ++mt){
    f4 scg = *(const f4*)&scsh[256 + mt*16 + q*4];
    f4 shg = *(const f4*)&scsh[384 + mt*16 + q*4];
    bfv4 e4 = *(const bfv4*)(ep + mt*16 + q*4);
    #pragma unroll
    for(int rr=0; rr<4; ++rr){
      float z = acc[mt][rr]*scg[rr] + shg[rr] + (float)e4[rr];
      ot[mt*16 + q*4 + rr][px0 + j] = silu_(z);
    }
  }
  __syncthreads();
  int t = threadIdx.x;
  #pragma unroll
  for(int e=0; e<8; ++e){
    int oc = e*16 + (t >> 4);
    int c4 = (t & 15)*4;
    f4 v = *(const f4*)&ot[oc][c4];
    *(f4*)&out[((size_t)(b*CC + oc))*HW + p0 + c4] = v;
  }
}

extern "C" void kernel_launch(void* const* d_in, const int* in_sizes, int n_in,
                              void* d_out, int out_size, void* d_ws, size_t ws_size,
                              hipStream_t stream) {
  const float* x   = (const float*)d_in[0];
  const float* fsr = (const float*)d_in[1];
  const float* w1  = (const float*)d_in[2];
  const float* g1  = (const float*)d_in[3];
  const float* b1  = (const float*)d_in[4];
  const float* m1  = (const float*)d_in[5];
  const float* v1  = (const float*)d_in[6];
  const float* w2  = (const float*)d_in[7];
  const float* g2  = (const float*)d_in[8];
  const float* b2  = (const float*)d_in[9];
  const float* m2  = (const float*)d_in[10];
  const float* v2  = (const float*)d_in[11];
  const float* w3  = (const float*)d_in[12];
  const float* g3  = (const float*)d_in[13];
  const float* b3  = (const float*)d_in[14];
  const float* m3  = (const float*)d_in[15];
  const float* v3  = (const float*)d_in[16];
  float* out = (float*)d_out;

  char* wp = (char*)d_ws;
  __bf16* fill16 = (__bf16*)wp;  wp += (size_t)BB*CC*HW*2;       // 52.4 MB
  __bf16* enh    = (__bf16*)wp;  wp += (size_t)BB*HW*CC*2;       // 52.4 MB
  __bf16* o1p    = (__bf16*)wp;  wp += (size_t)BB*PP*PP*CH*2;    // 26.9 MB
  __bf16* o2b    = (__bf16*)wp;  wp += (size_t)BB*HW*CH*2;       // 26.2 MB
  float*  xs     = (float*)wp;   wp += (size_t)BB*HW*4;
  float*  chw    = (float*)wp;   wp += 1024*4;
  __bf16* w1b    = (__bf16*)wp;  wp += (size_t)CH*CC*2;
  __bf16* w3b    = (__bf16*)wp;  wp += (size_t)CC*CH*2;
  __bf16* w2b    = (__bf16*)wp;  wp += (size_t)9*CH*CH*2;
  float*  scsh   = (float*)wp;   wp += 512*4;

  kprep    <<<dim3(64), dim3(256), 0, stream>>>(w1,g1,b1,m1,v1, w2,g2,b2,m2,v2,
                                                w3,g3,b3,m3,v3, w1b,w2b,w3b,scsh);
  kz_border<<<dim3(BB), dim3(256), 0, stream>>>(o1p);
  k12      <<<dim3(BB*CC), dim3(256), 0, stream>>>(x, fsr, fill16, chw);
  k3_xs    <<<dim3(100), dim3(256), 0, stream>>>(fill16, xs);
  k_enh    <<<dim3(BB*400), dim3(256), 0, stream>>>(fill16, chw, xs, enh);
  c1_mfma  <<<dim3(640), dim3(256), 0, stream>>>(enh, w1b, scsh, o1p);
  c2_mfma  <<<dim3(1280), dim3(256), 0, stream>>>(o1p, w2b, scsh, o2b);
  c3_mfma  <<<dim3(3200), dim3(256), 0, stream>>>(o2b, w3b, scsh, enh, out);
}